// Round 5
// baseline (163.596 us; speedup 1.0000x reference)
//
#include <hip/hip_runtime.h>

#define Wd 64
#define Hd 64
#define HWp 4096
#define CIN_ 128
#define COUT_ 128

typedef _Float16 f16;
typedef _Float16 h2   __attribute__((ext_vector_type(2)));
typedef _Float16 f16x8 __attribute__((ext_vector_type(8)));
typedef float f32x4   __attribute__((ext_vector_type(4)));

__device__ inline ushort f2h(float f) {
    f16 h = (f16)f;
    return __builtin_bit_cast(ushort, h);
}
__device__ inline h2 gb(const int4& g, int d) {
    return __builtin_bit_cast(h2, (&g.x)[d]);
}
__device__ inline h2 dup(float f) {
    f16 h = (f16)f;
    h2 r; r[0] = h; r[1] = h;
    return r;
}
struct H8 { h2 r[4]; };

// ---------------------------------------------------------------------------
// K_prep (1344 blocks):
//   blk 0..255    : transpose x NCHW f32 -> xt[b][yx][c] f16
//   blk 256..831  : repack main w -> f16 w_t2 in MFMA A-fragment order:
//                   i = (((s*2+wm)*4+ii)*64+lane)*8+j
//                   o = wm*64+ii*16+(lane&15), c = (s&3)*32+(lane>>4)*8+j,
//                   k = s>>2      (s = tap*4 + c-chunk)
//   blk 832..1343 : offset conv (4 used ch) + bilinear metadata per (b,k,p)
// ---------------------------------------------------------------------------
__global__ __launch_bounds__(256) void prep_offsets_kernel(
    const float* __restrict__ x, const float* __restrict__ w,
    const float* __restrict__ w_off, const float* __restrict__ b_off,
    ushort* __restrict__ xt, ushort* __restrict__ w_t2,
    int4* __restrict__ midx, float4* __restrict__ mw)
{
    __shared__ char smem[34816];
    int blk = blockIdx.x;
    int t = threadIdx.x;

    if (blk < 256) {
        ushort* tile = (ushort*)smem;                 // [128][136]
        int b = blk >> 5, yx0 = (blk & 31) << 7;
        const float* xb = x + (size_t)b * CIN_ * HWp + yx0;
        int lanelo = t & 31, grp = t >> 5;
        #pragma unroll
        for (int i = 0; i < 4; i++) {
            int cbase = i * 32 + grp * 4;
            float4 v0 = *(const float4*)(xb + (size_t)(cbase + 0) * HWp + lanelo * 4);
            float4 v1 = *(const float4*)(xb + (size_t)(cbase + 1) * HWp + lanelo * 4);
            float4 v2 = *(const float4*)(xb + (size_t)(cbase + 2) * HWp + lanelo * 4);
            float4 v3 = *(const float4*)(xb + (size_t)(cbase + 3) * HWp + lanelo * 4);
            ushort4 u;
            u.x = f2h(v0.x); u.y = f2h(v1.x); u.z = f2h(v2.x); u.w = f2h(v3.x);
            *(ushort4*)&tile[(lanelo * 4 + 0) * 136 + cbase] = u;
            u.x = f2h(v0.y); u.y = f2h(v1.y); u.z = f2h(v2.y); u.w = f2h(v3.y);
            *(ushort4*)&tile[(lanelo * 4 + 1) * 136 + cbase] = u;
            u.x = f2h(v0.z); u.y = f2h(v1.z); u.z = f2h(v2.z); u.w = f2h(v3.z);
            *(ushort4*)&tile[(lanelo * 4 + 2) * 136 + cbase] = u;
            u.x = f2h(v0.w); u.y = f2h(v1.w); u.z = f2h(v2.w); u.w = f2h(v3.w);
            *(ushort4*)&tile[(lanelo * 4 + 3) * 136 + cbase] = u;
        }
        __syncthreads();
        ushort* dst = xt + ((size_t)b * HWp + yx0) * CIN_;
        int c8 = (t & 15) * 8, yxg = t >> 4;
        #pragma unroll
        for (int i = 0; i < 8; i++) {
            int yxl = i * 16 + yxg;
            int4 v = *(int4*)&tile[yxl * 136 + c8];
            *(int4*)(dst + (size_t)yxl * CIN_ + c8) = v;
        }
    } else if (blk < 832) {
        int i = (blk - 256) * 256 + t;               // 147456 total
        int j    = i & 7;
        int lane = (i >> 3) & 63;
        int ii   = (i >> 9) & 3;
        int wm   = (i >> 11) & 1;
        int s    = i >> 12;
        int o = wm * 64 + ii * 16 + (lane & 15);
        int c = (s & 3) * 32 + (lane >> 4) * 8 + j;
        int k = s >> 2;
        w_t2[i] = f2h(w[o * 1152 + c * 9 + k]);
    } else {
        float* wl   = (float*)smem;                   // 4608 f
        float* part = (float*)(smem + 18432);         // 1024 f
        float* der  = (float*)(smem + 22528);         // 256 f
        int blk2 = blk - 832;
        int b = blk2 >> 6;
        int h = blk2 & 63;

        for (int i = t; i < 4608; i += 256) {
            int j = i / 1152;
            int r = i - j * 1152;                     // c*9 + tap
            wl[r * 4 + j] = w_off[i];
        }
        __syncthreads();

        int pi = t & 63, cc = t >> 6;
        const float* xb = x + (size_t)(b * CIN_ + cc * 32) * HWp;

        int idx9[9];
        float msk9[9];
        #pragma unroll
        for (int dy = 0; dy < 3; dy++) {
            int hy = h + dy - 1;
            int hyc = min(max(hy, 0), Hd - 1);
            bool vr = (hy >= 0) && (hy < Hd);
            #pragma unroll
            for (int dx = 0; dx < 3; dx++) {
                int wx = pi + dx - 1;
                int wxc = min(max(wx, 0), Wd - 1);
                bool v = vr && (wx >= 0) && (wx < Wd);
                idx9[dy * 3 + dx] = hyc * Wd + wxc;
                msk9[dy * 3 + dx] = v ? 1.0f : 0.0f;
            }
        }

        float o0 = 0.f, o1 = 0.f, o2 = 0.f, o3 = 0.f;
        #pragma unroll 2
        for (int c = 0; c < 32; c++) {
            const float* xp = xb + c * HWp;
            const float* wc = &wl[(cc * 32 + c) * 36];
            float xv[9];
            #pragma unroll
            for (int tp = 0; tp < 9; tp++) xv[tp] = xp[idx9[tp]] * msk9[tp];
            #pragma unroll
            for (int tp = 0; tp < 9; tp++) {
                float4 wj = *(const float4*)&wc[tp * 4];
                o0 += xv[tp] * wj.x; o1 += xv[tp] * wj.y;
                o2 += xv[tp] * wj.z; o3 += xv[tp] * wj.w;
            }
        }
        part[t * 4 + 0] = o0;
        part[t * 4 + 1] = o1;
        part[t * 4 + 2] = o2;
        part[t * 4 + 3] = o3;
        __syncthreads();

        if (t < 64) {
            float s0 = b_off[0], s1 = b_off[1], s2 = b_off[2], s3 = b_off[3];
            #pragma unroll
            for (int q = 0; q < 4; q++) {
                s0 += part[(q * 64 + t) * 4 + 0];
                s1 += part[(q * 64 + t) * 4 + 1];
                s2 += part[(q * 64 + t) * 4 + 2];
                s3 += part[(q * 64 + t) * 4 + 3];
            }
            der[t * 4 + 0] = s0;
            der[t * 4 + 1] = s1;
            der[t * 4 + 2] = fmaxf(s2, 0.f) + 1.f;
            der[t * 4 + 3] = fmaxf(s3, 0.f) + 1.f;
        }
        __syncthreads();

        #pragma unroll
        for (int s = 0; s < 3; s++) {
            int q = t + s * 256;
            if (q < 576) {
                int k = q >> 6;
                int pp = q & 63;
                float sy = der[pp * 4 + 0], sx = der[pp * 4 + 1];
                float sc1 = der[pp * 4 + 2], sc2 = der[pp * 4 + 3];
                int ky = k / 3, kx = k - ky * 3;
                float by = (float)(ky - 1), bx = (float)(kx - 1);
                bool corner = (ky != 1) && (kx != 1);
                bool edge = (ky != 1) ^ (kx != 1);
                float sk = corner ? sc1 : (edge ? sc2 : 0.0f);
                float py = (float)h + by * sk + sy;
                float px = (float)pp + bx * sk + sx;
                float y0f = floorf(py), x0f = floorf(px);
                float wy = py - y0f, wx = px - x0f;
                int y0 = (int)y0f, x0 = (int)x0f;
                int y1 = y0 + 1, x1 = x0 + 1;
                float vy0 = (y0 >= 0 && y0 < Hd) ? 1.f : 0.f;
                float vy1 = (y1 >= 0 && y1 < Hd) ? 1.f : 0.f;
                float vx0 = (x0 >= 0 && x0 < Wd) ? 1.f : 0.f;
                float vx1 = (x1 >= 0 && x1 < Wd) ? 1.f : 0.f;
                int cy0 = min(max(y0, 0), Hd - 1), cy1 = min(max(y1, 0), Hd - 1);
                int cx0 = min(max(x0, 0), Wd - 1), cx1 = min(max(x1, 0), Wd - 1);
                int4 ii;
                ii.x = cy0 * Wd + cx0;
                ii.y = cy0 * Wd + cx1;
                ii.z = cy1 * Wd + cx0;
                ii.w = cy1 * Wd + cx1;
                float4 ww;
                ww.x = (1.f - wy) * (1.f - wx) * vy0 * vx0;
                ww.y = (1.f - wy) * wx * vy0 * vx1;
                ww.z = wy * (1.f - wx) * vy1 * vx0;
                ww.w = wy * wx * vy1 * vx1;
                int addr = (b * 9 + k) * HWp + h * Wd + pp;
                midx[addr] = ii;
                mw[addr] = ww;
            }
        }
    }
}

// ---------------------------------------------------------------------------
// K3: barrier-free fused gather + f16 MFMA GEMM. NO LDS.
// Block = (b, h-row), 512 blocks x 256 thr = 4 waves: wm = M-half (64 o),
// ns = N-seg (32 p). Each lane builds its B-fragments DIRECTLY from the
// NHWC-f16 gather (B[k=(lane>>4)*8+j][n=lane&15] = 8 consecutive channels of
// one position); 4-corner bilinear combine in packed half2 (v_pk_fma_f16).
// A read global->reg in fragment order (L1/L2-resident). K = 36 chunks of
// 32 c, 1-deep register prefetch, corner pointers hoisted per tap.
// ---------------------------------------------------------------------------
__global__ __launch_bounds__(256, 2) void deform_gemm_mfma(
    const ushort* __restrict__ xt, const ushort* __restrict__ w_t2,
    const float* __restrict__ bias, const int4* __restrict__ midx,
    const float4* __restrict__ mw, float* __restrict__ out)
{
    int t = threadIdx.x;
    int b = blockIdx.x >> 6;
    int h = blockIdx.x & 63;
    int p0 = h << 6;
    const ushort* xtb = xt + (size_t)b * HWp * CIN_;

    int wv = t >> 6, lane = t & 63;
    int wm = wv & 1, ns = wv >> 1;        // M-half, N-32-segment
    int lm = lane & 15, lq = lane >> 4;

    f32x4 acc[4][2] = {};

    // per-tap state: corner base pointers + packed weights, for 2 B-frags
    const ushort* cb[2][4];
    h2 cw[2][4];
    auto loadmeta = [&](int k) {
        #pragma unroll
        for (int f = 0; f < 2; f++) {
            int addr = (b * 9 + k) * HWp + p0 + ns * 32 + f * 16 + lm;
            int4 mi = midx[addr];
            float4 v = mw[addr];
            cb[f][0] = xtb + mi.x * CIN_ + lq * 8;
            cb[f][1] = xtb + mi.y * CIN_ + lq * 8;
            cb[f][2] = xtb + mi.z * CIN_ + lq * 8;
            cb[f][3] = xtb + mi.w * CIN_ + lq * 8;
            cw[f][0] = dup(v.x); cw[f][1] = dup(v.y);
            cw[f][2] = dup(v.z); cw[f][3] = dup(v.w);
        }
    };

    int4 Gc[2][4], Gn[2][4];
    f16x8 Ac[4], An[4];
    h2 Wc[2][4], Wn[2][4];

    auto issue = [&](int s, int4 G[2][4], f16x8 A[4], h2 W[2][4]) {
        int q = s & 3;
        #pragma unroll
        for (int f = 0; f < 2; f++)
            #pragma unroll
            for (int r = 0; r < 4; r++) {
                G[f][r] = *(const int4*)(cb[f][r] + q * 32);
                W[f][r] = cw[f][r];
            }
        const ushort* ab = w_t2 + (size_t)((s * 2 + wm) * 4 * 64 + lane) * 8;
        #pragma unroll
        for (int i = 0; i < 4; i++)
            A[i] = *(const f16x8*)(ab + i * 512);
    };

    loadmeta(0);
    issue(0, Gc, Ac, Wc);

    for (int s = 0; s < 36; s++) {
        bool prod = (s + 1 < 36);
        if (prod) {
            if (((s + 1) & 3) == 0) loadmeta((s + 1) >> 2);
            issue(s + 1, Gn, An, Wn);
        }

        // build B-fragments from current gather (packed half2 math)
        f16x8 bfr[2];
        #pragma unroll
        for (int f = 0; f < 2; f++) {
            H8 tmp;
            #pragma unroll
            for (int d = 0; d < 4; d++) {
                h2 r = gb(Gc[f][0], d) * Wc[f][0];
                r = gb(Gc[f][1], d) * Wc[f][1] + r;
                r = gb(Gc[f][2], d) * Wc[f][2] + r;
                r = gb(Gc[f][3], d) * Wc[f][3] + r;
                tmp.r[d] = r;
            }
            bfr[f] = __builtin_bit_cast(f16x8, tmp);
        }

        #pragma unroll
        for (int i = 0; i < 4; i++)
            #pragma unroll
            for (int f = 0; f < 2; f++)
                acc[i][f] = __builtin_amdgcn_mfma_f32_16x16x32_f16(
                    Ac[i], bfr[f], acc[i][f], 0, 0, 0);

        if (prod) {
            #pragma unroll
            for (int f = 0; f < 2; f++)
                #pragma unroll
                for (int r = 0; r < 4; r++) {
                    Gc[f][r] = Gn[f][r];
                    Wc[f][r] = Wn[f][r];
                }
            #pragma unroll
            for (int i = 0; i < 4; i++) Ac[i] = An[i];
        }
    }

    // epilogue: C layout col(p)=lane&15, row(o)=(lane>>4)*4+reg
    #pragma unroll
    for (int i = 0; i < 4; i++) {
        #pragma unroll
        for (int r = 0; r < 4; r++) {
            int o = wm * 64 + i * 16 + lq * 4 + r;
            float bv = bias[o];
            float* orow = out + (size_t)(b * COUT_ + o) * HWp + p0 + ns * 32 + lm;
            #pragma unroll
            for (int f = 0; f < 2; f++)
                orow[f * 16] = acc[i][f][r] + bv;
        }
    }
}

extern "C" void kernel_launch(void* const* d_in, const int* in_sizes, int n_in,
                              void* d_out, int out_size, void* d_ws, size_t ws_size,
                              hipStream_t stream) {
    const float* x     = (const float*)d_in[0];
    const float* w_off = (const float*)d_in[1];
    const float* b_off = (const float*)d_in[2];
    const float* w     = (const float*)d_in[3];
    const float* bias  = (const float*)d_in[4];
    float* out = (float*)d_out;

    char* ws = (char*)d_ws;
    ushort* xt   = (ushort*)ws;                          // 8 MiB (f16)
    ushort* w_t2 = (ushort*)(ws + 8388608);              // 294912 B (f16)
    int4*   midx = (int4*)(ws + 8683520);                // 4.5 MiB
    float4* mwp  = (float4*)(ws + 13402112);             // 4.5 MiB

    prep_offsets_kernel<<<1344, 256, 0, stream>>>(x, w, w_off, b_off,
                                                  xt, w_t2, midx, mwp);
    deform_gemm_mfma<<<512, 256, 0, stream>>>(xt, w_t2, bias, midx, mwp, out);
}

// Round 6
// 123.183 us; speedup vs baseline: 1.3281x; 1.3281x over previous
//
#include <hip/hip_runtime.h>

#define Wd 64
#define Hd 64
#define HWp 4096
#define CIN_ 128
#define COUT_ 128

typedef _Float16 f16;
typedef _Float16 h2    __attribute__((ext_vector_type(2)));
typedef _Float16 f16x8 __attribute__((ext_vector_type(8)));
typedef float f32x4    __attribute__((ext_vector_type(4)));

__device__ inline ushort f2h(float f) {
    f16 h = (f16)f;
    return __builtin_bit_cast(ushort, h);
}
__device__ inline h2 gb(const int4& g, int d) {
    return __builtin_bit_cast(h2, (&g.x)[d]);
}
__device__ inline h2 dup(float f) {
    f16 h = (f16)f;
    h2 r; r[0] = h; r[1] = h;
    return r;
}
struct H8 { h2 r[4]; };

// ---------------------------------------------------------------------------
// K_prep (1344 blocks):
//   blk 0..255    : transpose x NCHW f32 -> xt[b][yx][c] f16
//   blk 256..831  : repack main w -> f16 w_t2 in MFMA A-fragment order:
//                   flat = (((s*2+wm)*4+ii)*64+lane)*8+j
//                   o = wm*64+ii*16+(lane&15), c = (s&3)*32+(lane>>4)*8+j,
//                   k = s>>2      (s = tap*4 + c-chunk)
//   blk 832..1343 : offset conv (4 used ch) + bilinear metadata per (b,k,p)
// ---------------------------------------------------------------------------
__global__ __launch_bounds__(256) void prep_offsets_kernel(
    const float* __restrict__ x, const float* __restrict__ w,
    const float* __restrict__ w_off, const float* __restrict__ b_off,
    ushort* __restrict__ xt, ushort* __restrict__ w_t2,
    int4* __restrict__ midx, float4* __restrict__ mw)
{
    __shared__ char smem[34816];
    int blk = blockIdx.x;
    int t = threadIdx.x;

    if (blk < 256) {
        ushort* tile = (ushort*)smem;                 // [128][136]
        int b = blk >> 5, yx0 = (blk & 31) << 7;
        const float* xb = x + (size_t)b * CIN_ * HWp + yx0;
        int lanelo = t & 31, grp = t >> 5;
        #pragma unroll
        for (int i = 0; i < 4; i++) {
            int cbase = i * 32 + grp * 4;
            float4 v0 = *(const float4*)(xb + (size_t)(cbase + 0) * HWp + lanelo * 4);
            float4 v1 = *(const float4*)(xb + (size_t)(cbase + 1) * HWp + lanelo * 4);
            float4 v2 = *(const float4*)(xb + (size_t)(cbase + 2) * HWp + lanelo * 4);
            float4 v3 = *(const float4*)(xb + (size_t)(cbase + 3) * HWp + lanelo * 4);
            ushort4 u;
            u.x = f2h(v0.x); u.y = f2h(v1.x); u.z = f2h(v2.x); u.w = f2h(v3.x);
            *(ushort4*)&tile[(lanelo * 4 + 0) * 136 + cbase] = u;
            u.x = f2h(v0.y); u.y = f2h(v1.y); u.z = f2h(v2.y); u.w = f2h(v3.y);
            *(ushort4*)&tile[(lanelo * 4 + 1) * 136 + cbase] = u;
            u.x = f2h(v0.z); u.y = f2h(v1.z); u.z = f2h(v2.z); u.w = f2h(v3.z);
            *(ushort4*)&tile[(lanelo * 4 + 2) * 136 + cbase] = u;
            u.x = f2h(v0.w); u.y = f2h(v1.w); u.z = f2h(v2.w); u.w = f2h(v3.w);
            *(ushort4*)&tile[(lanelo * 4 + 3) * 136 + cbase] = u;
        }
        __syncthreads();
        ushort* dst = xt + ((size_t)b * HWp + yx0) * CIN_;
        int c8 = (t & 15) * 8, yxg = t >> 4;
        #pragma unroll
        for (int i = 0; i < 8; i++) {
            int yxl = i * 16 + yxg;
            int4 v = *(int4*)&tile[yxl * 136 + c8];
            *(int4*)(dst + (size_t)yxl * CIN_ + c8) = v;
        }
    } else if (blk < 832) {
        int i = (blk - 256) * 256 + t;               // 147456 total
        int j    = i & 7;
        int lane = (i >> 3) & 63;
        int ii   = (i >> 9) & 3;
        int wm   = (i >> 11) & 1;
        int s    = i >> 12;
        int o = wm * 64 + ii * 16 + (lane & 15);
        int c = (s & 3) * 32 + (lane >> 4) * 8 + j;
        int k = s >> 2;
        w_t2[i] = f2h(w[o * 1152 + c * 9 + k]);
    } else {
        float* wl   = (float*)smem;                   // 4608 f
        float* part = (float*)(smem + 18432);         // 1024 f
        float* der  = (float*)(smem + 22528);         // 256 f
        int blk2 = blk - 832;
        int b = blk2 >> 6;
        int h = blk2 & 63;

        for (int i = t; i < 4608; i += 256) {
            int j = i / 1152;
            int r = i - j * 1152;                     // c*9 + tap
            wl[r * 4 + j] = w_off[i];
        }
        __syncthreads();

        int pi = t & 63, cc = t >> 6;
        const float* xb = x + (size_t)(b * CIN_ + cc * 32) * HWp;

        int idx9[9];
        float msk9[9];
        #pragma unroll
        for (int dy = 0; dy < 3; dy++) {
            int hy = h + dy - 1;
            int hyc = min(max(hy, 0), Hd - 1);
            bool vr = (hy >= 0) && (hy < Hd);
            #pragma unroll
            for (int dx = 0; dx < 3; dx++) {
                int wx = pi + dx - 1;
                int wxc = min(max(wx, 0), Wd - 1);
                bool v = vr && (wx >= 0) && (wx < Wd);
                idx9[dy * 3 + dx] = hyc * Wd + wxc;
                msk9[dy * 3 + dx] = v ? 1.0f : 0.0f;
            }
        }

        float o0 = 0.f, o1 = 0.f, o2 = 0.f, o3 = 0.f;
        #pragma unroll 2
        for (int c = 0; c < 32; c++) {
            const float* xp = xb + c * HWp;
            const float* wc = &wl[(cc * 32 + c) * 36];
            float xv[9];
            #pragma unroll
            for (int tp = 0; tp < 9; tp++) xv[tp] = xp[idx9[tp]] * msk9[tp];
            #pragma unroll
            for (int tp = 0; tp < 9; tp++) {
                float4 wj = *(const float4*)&wc[tp * 4];
                o0 += xv[tp] * wj.x; o1 += xv[tp] * wj.y;
                o2 += xv[tp] * wj.z; o3 += xv[tp] * wj.w;
            }
        }
        part[t * 4 + 0] = o0;
        part[t * 4 + 1] = o1;
        part[t * 4 + 2] = o2;
        part[t * 4 + 3] = o3;
        __syncthreads();

        if (t < 64) {
            float s0 = b_off[0], s1 = b_off[1], s2 = b_off[2], s3 = b_off[3];
            #pragma unroll
            for (int q = 0; q < 4; q++) {
                s0 += part[(q * 64 + t) * 4 + 0];
                s1 += part[(q * 64 + t) * 4 + 1];
                s2 += part[(q * 64 + t) * 4 + 2];
                s3 += part[(q * 64 + t) * 4 + 3];
            }
            der[t * 4 + 0] = s0;
            der[t * 4 + 1] = s1;
            der[t * 4 + 2] = fmaxf(s2, 0.f) + 1.f;
            der[t * 4 + 3] = fmaxf(s3, 0.f) + 1.f;
        }
        __syncthreads();

        #pragma unroll
        for (int s = 0; s < 3; s++) {
            int q = t + s * 256;
            if (q < 576) {
                int k = q >> 6;
                int pp = q & 63;
                float sy = der[pp * 4 + 0], sx = der[pp * 4 + 1];
                float sc1 = der[pp * 4 + 2], sc2 = der[pp * 4 + 3];
                int ky = k / 3, kx = k - ky * 3;
                float by = (float)(ky - 1), bx = (float)(kx - 1);
                bool corner = (ky != 1) && (kx != 1);
                bool edge = (ky != 1) ^ (kx != 1);
                float sk = corner ? sc1 : (edge ? sc2 : 0.0f);
                float py = (float)h + by * sk + sy;
                float px = (float)pp + bx * sk + sx;
                float y0f = floorf(py), x0f = floorf(px);
                float wy = py - y0f, wx = px - x0f;
                int y0 = (int)y0f, x0 = (int)x0f;
                int y1 = y0 + 1, x1 = x0 + 1;
                float vy0 = (y0 >= 0 && y0 < Hd) ? 1.f : 0.f;
                float vy1 = (y1 >= 0 && y1 < Hd) ? 1.f : 0.f;
                float vx0 = (x0 >= 0 && x0 < Wd) ? 1.f : 0.f;
                float vx1 = (x1 >= 0 && x1 < Wd) ? 1.f : 0.f;
                int cy0 = min(max(y0, 0), Hd - 1), cy1 = min(max(y1, 0), Hd - 1);
                int cx0 = min(max(x0, 0), Wd - 1), cx1 = min(max(x1, 0), Wd - 1);
                int4 ii;
                ii.x = cy0 * Wd + cx0;
                ii.y = cy0 * Wd + cx1;
                ii.z = cy1 * Wd + cx0;
                ii.w = cy1 * Wd + cx1;
                float4 ww;
                ww.x = (1.f - wy) * (1.f - wx) * vy0 * vx0;
                ww.y = (1.f - wy) * wx * vy0 * vx1;
                ww.z = wy * (1.f - wx) * vy1 * vx0;
                ww.w = wy * wx * vy1 * vx1;
                int addr = (b * 9 + k) * HWp + h * Wd + pp;
                midx[addr] = ii;
                mw[addr] = ww;
            }
        }
    }
}

// ---------------------------------------------------------------------------
// K3: fused gather + f16 MFMA GEMM, BK=64 stages.
// Block = (b, 2 h-rows): M=128, N=128, K=1152 in 18 stages of 2x32-c chunks.
// 512 thr = 8 waves (2 wm x 4 ns), wave tile 64x32.
// A staged global->LDS via async global_load_lds width=16 (no VGPR trip),
// S gathered (NHWC-f16, line-aligned) + pk-f16 bilinear combine -> LDS.
// Double-buffered; ONE barrier per 64-c stage (18 total).
// ---------------------------------------------------------------------------
__global__ __launch_bounds__(512, 1) void deform_gemm_mfma(
    const ushort* __restrict__ xt, const ushort* __restrict__ w_t2,
    const float* __restrict__ bias, const int4* __restrict__ midx,
    const float4* __restrict__ mw, float* __restrict__ out)
{
    __shared__ ushort A_lds[2][2][4096];      // [buf][chunk][ (wm*4+i)*512 + lane*8 + j ]
    __shared__ ushort S_lds[2][2][128 * 40];  // [buf][chunk][ p*40 + c8 ]

    int t = threadIdx.x;
    int b = blockIdx.x >> 5;
    int rp = blockIdx.x & 31;
    int p0 = rp << 7;
    const ushort* xtb = xt + (size_t)b * HWp * CIN_;

    int p  = t >> 2;                 // 0..127 position in tile
    int c8 = (t & 3) << 3;           // channel offset in 32-chunk

    int wv = t >> 6, lane = t & 63;
    int wm = wv & 1, ns = wv >> 1;   // M-half, N-32-seg (0..3)
    int lm = lane & 15, lq = lane >> 4;

    f32x4 acc[4][2] = {};

    // per-tap gather state for this thread's (p, c8) slot
    const ushort* cbp[4];
    h2 cwp[4];
    auto loadmeta = [&](int k) {
        int addr = (b * 9 + k) * HWp + p0 + p;
        int4 mi = midx[addr];
        float4 v = mw[addr];
        cbp[0] = xtb + mi.x * CIN_ + c8;
        cbp[1] = xtb + mi.y * CIN_ + c8;
        cbp[2] = xtb + mi.z * CIN_ + c8;
        cbp[3] = xtb + mi.w * CIN_ + c8;
        cwp[0] = dup(v.x); cwp[1] = dup(v.y);
        cwp[2] = dup(v.z); cwp[3] = dup(v.w);
    };

    // async A staging: stage st covers w_t2 ushorts [st*8192, st*8192+8192)
    auto stageA = [&](int buf, int st) {
        const ushort* src = w_t2 + (size_t)st * 8192;
        #pragma unroll
        for (int cc = 0; cc < 2; cc++) {
            const ushort* g = src + cc * 4096 + wv * 512 + lane * 8;
            ushort* l = &A_lds[buf][cc][wv * 512];
            __builtin_amdgcn_global_load_lds(
                (const __attribute__((address_space(1))) unsigned int*)g,
                (__attribute__((address_space(3))) unsigned int*)l, 16, 0, 0);
        }
    };

    int4 Gc[2][4], Gn[2][4];
    auto issue = [&](int st, int4 G[2][4]) {
        #pragma unroll
        for (int cc = 0; cc < 2; cc++) {
            int q = (2 * st + cc) & 3;
            #pragma unroll
            for (int r = 0; r < 4; r++)
                G[cc][r] = *(const int4*)(cbp[r] + q * 32);
        }
    };
    auto commitS = [&](int buf, const int4 G[2][4]) {
        #pragma unroll
        for (int cc = 0; cc < 2; cc++) {
            H8 tmp;
            #pragma unroll
            for (int d = 0; d < 4; d++) {
                h2 r = gb(G[cc][0], d) * cwp[0];
                r = gb(G[cc][1], d) * cwp[1] + r;
                r = gb(G[cc][2], d) * cwp[2] + r;
                r = gb(G[cc][3], d) * cwp[3] + r;
                tmp.r[d] = r;
            }
            *(int4*)&S_lds[buf][cc][p * 40 + c8] = __builtin_bit_cast(int4, tmp);
        }
    };

    // prologue: stage 0 -> buffer 0
    loadmeta(0);
    issue(0, Gc);
    stageA(0, 0);
    commitS(0, Gc);
    __syncthreads();

    for (int st = 0; st < 18; st++) {
        int cur = st & 1, nb = cur ^ 1;
        bool prod = (st + 1 < 18);
        if (prod) {
            if (((st + 1) & 1) == 0) loadmeta((st + 1) >> 1);
            issue(st + 1, Gn);
            stageA(nb, st + 1);
        }

        #pragma unroll
        for (int cc = 0; cc < 2; cc++) {
            f16x8 af[4], bfr[2];
            #pragma unroll
            for (int i = 0; i < 4; i++)
                af[i] = *(const f16x8*)&A_lds[cur][cc][(wm * 4 + i) * 512 + lane * 8];
            #pragma unroll
            for (int f = 0; f < 2; f++)
                bfr[f] = *(const f16x8*)&S_lds[cur][cc][(ns * 32 + f * 16 + lm) * 40 + lq * 8];
            #pragma unroll
            for (int i = 0; i < 4; i++)
                #pragma unroll
                for (int f = 0; f < 2; f++)
                    acc[i][f] = __builtin_amdgcn_mfma_f32_16x16x32_f16(
                        af[i], bfr[f], acc[i][f], 0, 0, 0);
        }

        if (prod) {
            commitS(nb, Gn);
            #pragma unroll
            for (int cc = 0; cc < 2; cc++)
                #pragma unroll
                for (int r = 0; r < 4; r++) Gc[cc][r] = Gn[cc][r];
        }
        __syncthreads();
    }

    // epilogue: C layout col(p)=lane&15, row(o)=(lane>>4)*4+reg
    #pragma unroll
    for (int i = 0; i < 4; i++) {
        #pragma unroll
        for (int r = 0; r < 4; r++) {
            int o = wm * 64 + i * 16 + lq * 4 + r;
            float bv = bias[o];
            float* orow = out + (size_t)(b * COUT_ + o) * HWp + p0 + ns * 32 + lm;
            #pragma unroll
            for (int f = 0; f < 2; f++)
                orow[f * 16] = acc[i][f][r] + bv;
        }
    }
}

extern "C" void kernel_launch(void* const* d_in, const int* in_sizes, int n_in,
                              void* d_out, int out_size, void* d_ws, size_t ws_size,
                              hipStream_t stream) {
    const float* x     = (const float*)d_in[0];
    const float* w_off = (const float*)d_in[1];
    const float* b_off = (const float*)d_in[2];
    const float* w     = (const float*)d_in[3];
    const float* bias  = (const float*)d_in[4];
    float* out = (float*)d_out;

    char* ws = (char*)d_ws;
    ushort* xt   = (ushort*)ws;                          // 8 MiB (f16 NHWC)
    ushort* w_t2 = (ushort*)(ws + 8388608);              // 294912 B (f16 frag order)
    int4*   midx = (int4*)(ws + 8683520);                // 4.5 MiB
    float4* mwp  = (float4*)(ws + 13402112);             // 4.5 MiB

    prep_offsets_kernel<<<1344, 256, 0, stream>>>(x, w, w_off, b_off,
                                                  xt, w_t2, midx, mwp);
    deform_gemm_mfma<<<256, 512, 0, stream>>>(xt, w_t2, bias, midx, mwp, out);
}